// Round 2
// baseline (5357.267 us; speedup 1.0000x reference)
//
#include <hip/hip_runtime.h>
#include <hip/hip_bf16.h>
#include <math.h>

#define DMODEL 4096
#define NROWS  8192          // B*N = 4*2048
#define DFF    5461
#define CHUNK  1024
#define NCHUNK 8
#define LNEPS  1e-5f

// fp32 tiled GEMM params
#define BM 128
#define BN 128
#define BK 32
#define LDA (BM + 4)   // 132 floats: pad to dodge power-of-2 bank strides

__device__ inline unsigned short f2bf(float f) {
    unsigned int x = __builtin_bit_cast(unsigned int, f);
    unsigned int r = x + 0x7FFFu + ((x >> 16) & 1u);   // RNE
    return (unsigned short)(r >> 16);
}
__device__ inline float bf2f(unsigned short u) {
    return __builtin_bit_cast(float, ((unsigned int)u) << 16);
}

// ---------------- block-diagonal gate GEMM, fp32 VALU, silu fused on A ----------------
// pre[g, row, kb*1024 + o] = sum_i silu(x[row, kb*1024+i]) * Wg[g,kb,o,i]
// grid: x = 1024/BN (=8) n-tiles, y = CHUNK/BM (=8) m-tiles, z = 16 (g*4+kb)
__global__ __launch_bounds__(256, 2) void gemm_gates_f32_k(
    const float* __restrict__ x,
    const float* __restrict__ Wg,
    float* __restrict__ pre, int row0)
{
    __shared__ __align__(16) float As[BK][LDA];
    __shared__ __align__(16) float Bs[BK][LDA];

    const int gz = blockIdx.z;
    const int kb = gz & 3, g = gz >> 2;
    const int tM = blockIdx.y, tN = blockIdx.x;
    const int t = threadIdx.x;
    const int r8 = t >> 3;        // 0..31 (tile row within staging pass)
    const int c4 = (t & 7) * 4;   // k-offset of this thread's float4
    const int tm = (t & 15) * 8;  // 8x8 micro-tile origin
    const int tn = (t >> 4) * 8;

    const float* Abase = x + (size_t)(row0 + tM * BM) * DMODEL + kb * 1024;
    const float* Bbase = Wg + (size_t)gz * (1024 * 1024) + (size_t)(tN * BN) * 1024;

    float acc[8][8] = {};

    for (int kt = 0; kt < 1024; kt += BK) {
#pragma unroll
        for (int it = 0; it < 4; ++it) {
            const int row = it * 32 + r8;
            float4 av = *(const float4*)(Abase + (size_t)row * DMODEL + kt + c4);
            float4 bv = *(const float4*)(Bbase + (size_t)row * 1024 + kt + c4);
            av.x = av.x / (1.f + expf(-av.x));   // silu, fp32, matches reference
            av.y = av.y / (1.f + expf(-av.y));
            av.z = av.z / (1.f + expf(-av.z));
            av.w = av.w / (1.f + expf(-av.w));
            As[c4 + 0][row] = av.x;
            As[c4 + 1][row] = av.y;
            As[c4 + 2][row] = av.z;
            As[c4 + 3][row] = av.w;
            Bs[c4 + 0][row] = bv.x;
            Bs[c4 + 1][row] = bv.y;
            Bs[c4 + 2][row] = bv.z;
            Bs[c4 + 3][row] = bv.w;
        }
        __syncthreads();
#pragma unroll 8
        for (int k = 0; k < BK; ++k) {
            float a[8], b[8];
            *(float4*)&a[0] = *(const float4*)&As[k][tm];
            *(float4*)&a[4] = *(const float4*)&As[k][tm + 4];
            *(float4*)&b[0] = *(const float4*)&Bs[k][tn];
            *(float4*)&b[4] = *(const float4*)&Bs[k][tn + 4];
#pragma unroll
            for (int i = 0; i < 8; ++i)
#pragma unroll
                for (int j = 0; j < 8; ++j)
                    acc[i][j] = fmaf(a[i], b[j], acc[i][j]);
        }
        __syncthreads();
    }

#pragma unroll
    for (int i = 0; i < 8; ++i) {
        float* dst = pre + ((size_t)g * CHUNK + tM * BM + tm + i) * DMODEL
                     + kb * 1024 + tN * BN + tn;
        float4 v0 = make_float4(acc[i][0], acc[i][1], acc[i][2], acc[i][3]);
        float4 v1 = make_float4(acc[i][4], acc[i][5], acc[i][6], acc[i][7]);
        *(float4*)dst = v0;
        *(float4*)(dst + 4) = v1;
    }
}

// ---------------- block reduction helper (256 threads = 4 waves) ----------------
template <int N>
__device__ inline void block_reduce(float* s, float* red) {
    const int t = threadIdx.x, w = t >> 6, l = t & 63;
#pragma unroll
    for (int i = 0; i < N; ++i) {
        float v = s[i];
#pragma unroll
        for (int off = 32; off > 0; off >>= 1) v += __shfl_xor(v, off, 64);
        if (l == 0) red[w * N + i] = v;
    }
    __syncthreads();
#pragma unroll
    for (int i = 0; i < N; ++i)
        s[i] = red[0 * N + i] + red[1 * N + i] + red[2 * N + i] + red[3 * N + i];
    __syncthreads();
}

// ---------------- fused LN + gates + ct/nt row accumulation (per chunk) ----------------
#define EROWS 8
__global__ __launch_bounds__(256) void lnpass_k(
    const float* __restrict__ pre, const float* __restrict__ bg,
    const float* __restrict__ lng, const float* __restrict__ lnb,
    unsigned short* __restrict__ obuf,
    float* __restrict__ ctv, float* __restrict__ ntv, int row0)
{
    __shared__ float red[32];
    const int t = threadIdx.x;
    const float n1 = 1.f / DMODEL;
    float ct_acc[16] = {}, nt_acc[16] = {};

    for (int rr = 0; rr < EROWS; ++rr) {
        const int rl = blockIdx.x * EROWS + rr;
        const float* p0 = pre + ((size_t)0 * CHUNK + rl) * DMODEL;
        const float* p1 = pre + ((size_t)1 * CHUNK + rl) * DMODEL;
        const float* p2 = pre + ((size_t)2 * CHUNK + rl) * DMODEL;
        const float* p3 = pre + ((size_t)3 * CHUNK + rl) * DMODEL;

        float s[8] = {};
        for (int j = 0; j < 16; ++j) {
            const int d = t + 256 * j;
            float v0 = p0[d] + bg[d];
            float v1 = p1[d] + bg[DMODEL + d];
            float v2 = p2[d] + bg[2 * DMODEL + d];
            float v3 = p3[d] + bg[3 * DMODEL + d];
            s[0] += v0; s[1] += v0 * v0;
            s[2] += v1; s[3] += v1 * v1;
            s[4] += v2; s[5] += v2 * v2;
            s[6] += v3; s[7] += v3 * v3;
        }
        block_reduce<8>(s, red);
        const float mu0 = s[0] * n1, rs0 = rsqrtf(s[1] * n1 - mu0 * mu0 + LNEPS);
        const float mu1 = s[2] * n1, rs1 = rsqrtf(s[3] * n1 - mu1 * mu1 + LNEPS);
        const float mu2 = s[4] * n1, rs2 = rsqrtf(s[5] * n1 - mu2 * mu2 + LNEPS);
        const float mu3 = s[6] * n1, rs3 = rsqrtf(s[7] * n1 - mu3 * mu3 + LNEPS);

        float ctl[16], ntl[16];
        float s2[4] = {};
        for (int j = 0; j < 16; ++j) {
            const int d = t + 256 * j;
            float li = (p0[d] + bg[d] - mu0) * rs0 * lng[d] + lnb[d];
            float lf = (p1[d] + bg[DMODEL + d] - mu1) * rs1 * lng[DMODEL + d] + lnb[DMODEL + d];
            float iv = expf(fminf(li - lf, 0.f));   // i = exp(log_i - max(log_i, log_f))
            float zv = tanhf((p3[d] + bg[3 * DMODEL + d] - mu3) * rs3 * lng[3 * DMODEL + d]
                             + lnb[3 * DMODEL + d]);
            float c = iv * zv;
            ctl[j] = c; ntl[j] = iv;
            s2[0] += c;  s2[1] += c * c;
            s2[2] += iv; s2[3] += iv * iv;
        }
        block_reduce<4>(s2, red);
        const float cmu = s2[0] * n1, crs = rsqrtf(s2[1] * n1 - cmu * cmu + LNEPS);
        const float nmu = s2[2] * n1, nrs = rsqrtf(s2[3] * n1 - nmu * nmu + LNEPS);

        for (int j = 0; j < 16; ++j) {
            const int d = t + 256 * j;
            ct_acc[j] += (ctl[j] - cmu) * crs * lng[4 * DMODEL + d] + lnb[4 * DMODEL + d];
            nt_acc[j] += (ntl[j] - nmu) * nrs * lng[5 * DMODEL + d] + lnb[5 * DMODEL + d];
            float ov = (p2[d] + bg[2 * DMODEL + d] - mu2) * rs2 * lng[2 * DMODEL + d]
                       + lnb[2 * DMODEL + d];
            ov = 1.f / (1.f + expf(-ov));
            obuf[(size_t)(row0 + rl) * DMODEL + d] = f2bf(ov);
        }
    }
    for (int j = 0; j < 16; ++j) {
        const int d = t + 256 * j;
        atomicAdd(&ctv[d], ct_acc[j]);
        atomicAdd(&ntv[d], nt_acc[j]);
    }
}

// ---------------- ht = o * (ctv/ntv), LN6 per row, accumulate row-mean ----------------
#define HROWS 16
__global__ __launch_bounds__(256) void htpass_k(
    const unsigned short* __restrict__ obuf,
    const float* __restrict__ ctv, const float* __restrict__ ntv,
    const float* __restrict__ lng, const float* __restrict__ lnb,
    float* __restrict__ htv)
{
    __shared__ float red[8];
    const int t = threadIdx.x;
    const float n1 = 1.f / DMODEL;
    float r[16], hacc[16] = {};
    for (int j = 0; j < 16; ++j) {
        const int d = t + 256 * j;
        r[j] = ctv[d] / ntv[d];      // ratio of sums == ratio of means
    }
    for (int rr = 0; rr < HROWS; ++rr) {
        const int row = blockIdx.x * HROWS + rr;
        float h[16]; float s[2] = {};
        for (int j = 0; j < 16; ++j) {
            const int d = t + 256 * j;
            h[j] = bf2f(obuf[(size_t)row * DMODEL + d]) * r[j];
            s[0] += h[j]; s[1] += h[j] * h[j];
        }
        block_reduce<2>(s, red);
        const float mu = s[0] * n1, rsv = rsqrtf(s[1] * n1 - mu * mu + LNEPS);
        for (int j = 0; j < 16; ++j) {
            const int d = t + 256 * j;
            hacc[j] += (h[j] - mu) * rsv * lng[6 * DMODEL + d] + lnb[6 * DMODEL + d];
        }
    }
    for (int j = 0; j < 16; ++j) {
        const int d = t + 256 * j;
        atomicAdd(&htv[d], hacc[j]);
    }
}

// ---------------- slstm_out = LN7(mean ht) ----------------
__global__ __launch_bounds__(256) void finalvec_k(
    const float* __restrict__ htv, const float* __restrict__ lng,
    const float* __restrict__ lnb, float* __restrict__ sout)
{
    __shared__ float red[8];
    const int t = threadIdx.x;
    const float n1 = 1.f / DMODEL;
    float v[16]; float s[2] = {};
    for (int j = 0; j < 16; ++j) {
        const int d = t + 256 * j;
        v[j] = htv[d] * (1.f / (float)NROWS);
        s[0] += v[j]; s[1] += v[j] * v[j];
    }
    block_reduce<2>(s, red);
    const float mu = s[0] * n1, rs = rsqrtf(s[1] * n1 - mu * mu + LNEPS);
    for (int j = 0; j < 16; ++j) {
        const int d = t + 256 * j;
        sout[d] = (v[j] - mu) * rs * lng[7 * DMODEL + d] + lnb[7 * DMODEL + d];
    }
}

// ---------------- left/right GEMV + exact gelu, one wave per output f ----------------
__global__ __launch_bounds__(256) void ffn1_k(
    const float* __restrict__ sout,
    const float* __restrict__ Wl, const float* __restrict__ bl,
    const float* __restrict__ Wr, const float* __restrict__ br,
    float* __restrict__ u)
{
    const int t = threadIdx.x, w = t >> 6, l = t & 63;
    const int f = blockIdx.x * 4 + w;
    if (f >= DFF) return;
    const float4* wl4 = (const float4*)(Wl + (size_t)f * DMODEL);
    const float4* wr4 = (const float4*)(Wr + (size_t)f * DMODEL);
    const float4* s4 = (const float4*)sout;
    float a = 0.f, b = 0.f;
#pragma unroll
    for (int jj = 0; jj < 16; ++jj) {
        const int i4 = l + 64 * jj;
        float4 sv = s4[i4], av = wl4[i4], bv = wr4[i4];
        a += sv.x * av.x + sv.y * av.y + sv.z * av.z + sv.w * av.w;
        b += sv.x * bv.x + sv.y * bv.y + sv.z * bv.z + sv.w * bv.w;
    }
#pragma unroll
    for (int off = 32; off > 0; off >>= 1) {
        a += __shfl_xor(a, off, 64);
        b += __shfl_xor(b, off, 64);
    }
    if (l == 0) {
        float lv = a + bl[f];
        float rv = b + br[f];
        float g = 0.5f * rv * (1.f + erff(rv * 0.70710678118654752f));  // exact gelu
        u[f] = lv * g;
    }
}

// ---------------- LN over DFF ----------------
__global__ __launch_bounds__(256) void lnout_k(
    const float* __restrict__ u, const float* __restrict__ g,
    const float* __restrict__ b, float* __restrict__ y)
{
    __shared__ float red[8];
    const int t = threadIdx.x;
    float s[2] = {};
    for (int d = t; d < DFF; d += 256) { float v = u[d]; s[0] += v; s[1] += v * v; }
    block_reduce<2>(s, red);
    const float n1 = 1.f / (float)DFF;
    const float mu = s[0] * n1, rs = rsqrtf(s[1] * n1 - mu * mu + LNEPS);
    for (int d = t; d < DFF; d += 256) y[d] = (u[d] - mu) * rs * g[d] + b[d];
}

// ---------------- proj GEMV, one wave per output d ----------------
__global__ __launch_bounds__(256) void ffn2_k(
    const float* __restrict__ y, const float* __restrict__ Wp,
    const float* __restrict__ bp, float* __restrict__ out)
{
    const int t = threadIdx.x, w = t >> 6, l = t & 63;
    const int d = blockIdx.x * 4 + w;
    const float* row = Wp + (size_t)d * DFF;
    float s = 0.f;
    for (int j = l; j < DFF; j += 64) s += row[j] * y[j];
#pragma unroll
    for (int off = 32; off > 0; off >>= 1) s += __shfl_xor(s, off, 64);
    if (l == 0) out[d] = s + bp[d];
}

extern "C" void kernel_launch(void* const* d_in, const int* in_sizes, int n_in,
                              void* d_out, int out_size, void* d_ws, size_t ws_size,
                              hipStream_t stream)
{
    const float* x   = (const float*)d_in[0];
    const float* Wg  = (const float*)d_in[1];
    const float* bg  = (const float*)d_in[2];
    // d_in[3] = Wr_gates: provably unused (ht_1 == 0)
    const float* lng = (const float*)d_in[4];
    const float* lnb = (const float*)d_in[5];
    const float* log_ = (const float*)d_in[6];
    const float* lob  = (const float*)d_in[7];
    const float* Wl  = (const float*)d_in[8];
    const float* bl  = (const float*)d_in[9];
    const float* Wr  = (const float*)d_in[10];
    const float* br  = (const float*)d_in[11];
    const float* Wp  = (const float*)d_in[12];
    const float* bp  = (const float*)d_in[13];
    float* out = (float*)d_out;

    char* ws = (char*)d_ws;
    size_t off = 0;
    unsigned short* obuf = (unsigned short*)(ws + off); off += (size_t)NROWS * DMODEL * 2;  // 64 MB
    float* pre  = (float*)(ws + off); off += (size_t)4 * CHUNK * DMODEL * 4;                // 64 MB
    float* ctv  = (float*)(ws + off); off += DMODEL * 4;
    float* ntv  = (float*)(ws + off); off += DMODEL * 4;
    float* htv  = (float*)(ws + off); off += DMODEL * 4;
    float* sout = (float*)(ws + off); off += DMODEL * 4;
    float* u    = (float*)(ws + off); off += DFF * 4;
    float* y    = (float*)(ws + off); off += DFF * 4;

    // zero the global accumulators (ctv, ntv, htv are contiguous)
    hipMemsetAsync(ctv, 0, 3 * DMODEL * 4, stream);

    for (int c = 0; c < NCHUNK; ++c) {
        const int row0 = c * CHUNK;
        dim3 grid(1024 / BN, CHUNK / BM, 16);
        gemm_gates_f32_k<<<grid, 256, 0, stream>>>(x, Wg, pre, row0);
        lnpass_k<<<CHUNK / EROWS, 256, 0, stream>>>(pre, bg, lng, lnb, obuf, ctv, ntv, row0);
    }

    htpass_k<<<NROWS / HROWS, 256, 0, stream>>>(obuf, ctv, ntv, lng, lnb, htv);
    finalvec_k<<<1, 256, 0, stream>>>(htv, lng, lnb, sout);
    ffn1_k<<<(DFF + 3) / 4, 256, 0, stream>>>(sout, Wl, bl, Wr, br, u);
    lnout_k<<<1, 256, 0, stream>>>(u, log_, lob, y);
    ffn2_k<<<DMODEL / 4, 256, 0, stream>>>(y, Wp, bp, out);

    (void)in_sizes; (void)n_in; (void)out_size; (void)ws_size;
}

// Round 3
// 2636.070 us; speedup vs baseline: 2.0323x; 2.0323x over previous
//
#include <hip/hip_runtime.h>
#include <hip/hip_bf16.h>
#include <math.h>

#define DMODEL 4096
#define NROWS  8192          // B*N = 4*2048
#define DFF    5461
#define CHUNK  512
#define NCHUNK 16
#define LNEPS  1e-5f

// split-fp16 MFMA GEMM params
#define GBM 128
#define GBN 128
#define GBK 32
#define LOSCALE 2048.0f      // 2^11
#define LOINV   4.8828125e-4f // 2^-11

typedef _Float16 h8 __attribute__((ext_vector_type(8)));
typedef _Float16 h4 __attribute__((ext_vector_type(4)));
typedef float floatx4 __attribute__((ext_vector_type(4)));

__device__ inline unsigned short f2bf(float f) {
    unsigned int x = __builtin_bit_cast(unsigned int, f);
    unsigned int r = x + 0x7FFFu + ((x >> 16) & 1u);   // RNE
    return (unsigned short)(r >> 16);
}
__device__ inline float bf2f(unsigned short u) {
    return __builtin_bit_cast(float, ((unsigned int)u) << 16);
}

#define GLL(gp, lp) __builtin_amdgcn_global_load_lds( \
    (const __attribute__((address_space(1))) void*)(gp), \
    (__attribute__((address_space(3))) void*)(lp), 16, 0, 0)

// ---------------- prep: silu(x) fp32 -> fp16 hi/lo split ----------------
__global__ __launch_bounds__(256) void silu_split_k(const float* __restrict__ x,
                                                    _Float16* __restrict__ xh,
                                                    _Float16* __restrict__ xl) {
    size_t i = (size_t)blockIdx.x * 256 + threadIdx.x;   // float4 index
    float4 v = ((const float4*)x)[i];
    float s[4];
    s[0] = v.x / (1.f + expf(-v.x));
    s[1] = v.y / (1.f + expf(-v.y));
    s[2] = v.z / (1.f + expf(-v.z));
    s[3] = v.w / (1.f + expf(-v.w));
    h4 hi, lo;
#pragma unroll
    for (int j = 0; j < 4; ++j) {
        _Float16 h = (_Float16)s[j];
        hi[j] = h;
        lo[j] = (_Float16)((s[j] - (float)h) * LOSCALE);
    }
    ((h4*)xh)[i] = hi;
    ((h4*)xl)[i] = lo;
}

// ---------------- prep: W_gates fp32 -> fp16 hi/lo split ----------------
__global__ __launch_bounds__(256) void wsplit_k(const float* __restrict__ Wg,
                                                _Float16* __restrict__ wh,
                                                _Float16* __restrict__ wl) {
    size_t i = (size_t)blockIdx.x * 256 + threadIdx.x;
    float4 v = ((const float4*)Wg)[i];
    float s[4] = {v.x, v.y, v.z, v.w};
    h4 hi, lo;
#pragma unroll
    for (int j = 0; j < 4; ++j) {
        _Float16 h = (_Float16)s[j];
        hi[j] = h;
        lo[j] = (_Float16)((s[j] - (float)h) * LOSCALE);
    }
    ((h4*)wh)[i] = hi;
    ((h4*)wl)[i] = lo;
}

// ---------------- block-diagonal gate GEMM, split-fp16 MFMA (~fp32 precision) ----------------
// pre[g, row, kb*1024 + o] = sum_i silu(x)[row, kb*1024+i] * Wg[g,kb,o,i]
// grid: x = 1024/GBN (=8), y = CHUNK/GBM (=4), z = 16 (g*4+kb)
__global__ __launch_bounds__(256, 2) void gemm_split_k(
    const _Float16* __restrict__ xh, const _Float16* __restrict__ xl,
    const _Float16* __restrict__ wh, const _Float16* __restrict__ wl,
    float* __restrict__ pre, int row0)
{
    __shared__ __align__(16) _Float16 Ah[GBM * GBK];   // 8 KB each, 32 KB total
    __shared__ __align__(16) _Float16 Al[GBM * GBK];
    __shared__ __align__(16) _Float16 Bh[GBN * GBK];
    __shared__ __align__(16) _Float16 Bl[GBN * GBK];

    const int gz = blockIdx.z;
    const int kb = gz & 3, g = gz >> 2;
    const int tM = blockIdx.y, tN = blockIdx.x;
    const int t = threadIdx.x;
    const int w = t >> 6, l = t & 63;
    const int lane15 = l & 15, quad = l >> 4;
    const int wm = w >> 1, wn = w & 1;

    const size_t Aoff = (size_t)(row0 + tM * GBM) * DMODEL + kb * 1024;
    const size_t Boff = (size_t)gz * (1024 * 1024) + (size_t)(tN * GBN) * 1024;

    floatx4 acc_h[4][4] = {};
    floatx4 acc_x[4][4] = {};

    for (int kt = 0; kt < 1024; kt += GBK) {
        const _Float16* ahs = xh + Aoff + kt;
        const _Float16* als = xl + Aoff + kt;
        const _Float16* bhs = wh + Boff + kt;
        const _Float16* bls = wl + Boff + kt;
#pragma unroll
        for (int it = 0; it < 2; ++it) {
            const int chunk = it * 256 + t;       // 0..511 16B-chunks per tile
            const int r = chunk >> 2;             // tile row 0..127
            const int c = (chunk & 3) * 8;        // k-offset in halfs
            const int lo = (it * 256 + w * 64) * 8;  // wave-uniform LDS base (elements)
            const size_t ga = (size_t)r * DMODEL + c;
            const size_t gb = (size_t)r * 1024 + c;
            GLL(ahs + ga, Ah + lo);
            GLL(als + ga, Al + lo);
            GLL(bhs + gb, Bh + lo);
            GLL(bls + gb, Bl + lo);
        }
        __syncthreads();

        h8 af[4], alf[4], bf[4], blf[4];
#pragma unroll
        for (int mi = 0; mi < 4; ++mi) {
            const int ro = (wm * 64 + mi * 16 + lane15) * GBK + quad * 8;
            af[mi]  = *(const h8*)&Ah[ro];
            alf[mi] = *(const h8*)&Al[ro];
        }
#pragma unroll
        for (int ni = 0; ni < 4; ++ni) {
            const int ro = (wn * 64 + ni * 16 + lane15) * GBK + quad * 8;
            bf[ni]  = *(const h8*)&Bh[ro];
            blf[ni] = *(const h8*)&Bl[ro];
        }
#pragma unroll
        for (int mi = 0; mi < 4; ++mi)
#pragma unroll
            for (int ni = 0; ni < 4; ++ni) {
                acc_h[mi][ni] = __builtin_amdgcn_mfma_f32_16x16x32_f16(
                    af[mi], bf[ni], acc_h[mi][ni], 0, 0, 0);
                acc_x[mi][ni] = __builtin_amdgcn_mfma_f32_16x16x32_f16(
                    af[mi], blf[ni], acc_x[mi][ni], 0, 0, 0);
                acc_x[mi][ni] = __builtin_amdgcn_mfma_f32_16x16x32_f16(
                    alf[mi], bf[ni], acc_x[mi][ni], 0, 0, 0);
            }
        __syncthreads();
    }

#pragma unroll
    for (int mi = 0; mi < 4; ++mi) {
#pragma unroll
        for (int r = 0; r < 4; ++r) {
            const int rowl = tM * GBM + wm * 64 + mi * 16 + quad * 4 + r;
            float* dst = pre + ((size_t)g * CHUNK + rowl) * DMODEL
                         + kb * 1024 + tN * GBN + wn * 64 + lane15;
#pragma unroll
            for (int ni = 0; ni < 4; ++ni)
                dst[ni * 16] = acc_h[mi][ni][r] + acc_x[mi][ni][r] * LOINV;
        }
    }
}

// ---------------- block reduction helper (256 threads = 4 waves) ----------------
template <int N>
__device__ inline void block_reduce(float* s, float* red) {
    const int t = threadIdx.x, w = t >> 6, l = t & 63;
#pragma unroll
    for (int i = 0; i < N; ++i) {
        float v = s[i];
#pragma unroll
        for (int off = 32; off > 0; off >>= 1) v += __shfl_xor(v, off, 64);
        if (l == 0) red[w * N + i] = v;
    }
    __syncthreads();
#pragma unroll
    for (int i = 0; i < N; ++i)
        s[i] = red[0 * N + i] + red[1 * N + i] + red[2 * N + i] + red[3 * N + i];
    __syncthreads();
}

// ---------------- fused LN + gates + ct/nt row accumulation (per chunk) ----------------
#define EROWS 2
__global__ __launch_bounds__(256) void lnpass_k(
    const float* __restrict__ pre, const float* __restrict__ bg,
    const float* __restrict__ lng, const float* __restrict__ lnb,
    unsigned short* __restrict__ obuf,
    float* __restrict__ ctv, float* __restrict__ ntv, int row0)
{
    __shared__ float red[32];
    const int t = threadIdx.x;
    const float n1 = 1.f / DMODEL;
    float ct_acc[16] = {}, nt_acc[16] = {};

    for (int rr = 0; rr < EROWS; ++rr) {
        const int rl = blockIdx.x * EROWS + rr;
        const float* p0 = pre + ((size_t)0 * CHUNK + rl) * DMODEL;
        const float* p1 = pre + ((size_t)1 * CHUNK + rl) * DMODEL;
        const float* p2 = pre + ((size_t)2 * CHUNK + rl) * DMODEL;
        const float* p3 = pre + ((size_t)3 * CHUNK + rl) * DMODEL;

        float s[8] = {};
        for (int j = 0; j < 16; ++j) {
            const int d = t + 256 * j;
            float v0 = p0[d] + bg[d];
            float v1 = p1[d] + bg[DMODEL + d];
            float v2 = p2[d] + bg[2 * DMODEL + d];
            float v3 = p3[d] + bg[3 * DMODEL + d];
            s[0] += v0; s[1] += v0 * v0;
            s[2] += v1; s[3] += v1 * v1;
            s[4] += v2; s[5] += v2 * v2;
            s[6] += v3; s[7] += v3 * v3;
        }
        block_reduce<8>(s, red);
        const float mu0 = s[0] * n1, rs0 = rsqrtf(s[1] * n1 - mu0 * mu0 + LNEPS);
        const float mu1 = s[2] * n1, rs1 = rsqrtf(s[3] * n1 - mu1 * mu1 + LNEPS);
        const float mu2 = s[4] * n1, rs2 = rsqrtf(s[5] * n1 - mu2 * mu2 + LNEPS);
        const float mu3 = s[6] * n1, rs3 = rsqrtf(s[7] * n1 - mu3 * mu3 + LNEPS);

        float ctl[16], ntl[16];
        float s2[4] = {};
        for (int j = 0; j < 16; ++j) {
            const int d = t + 256 * j;
            float li = (p0[d] + bg[d] - mu0) * rs0 * lng[d] + lnb[d];
            float lf = (p1[d] + bg[DMODEL + d] - mu1) * rs1 * lng[DMODEL + d] + lnb[DMODEL + d];
            float iv = expf(fminf(li - lf, 0.f));   // i = exp(log_i - max(log_i, log_f))
            float zv = tanhf((p3[d] + bg[3 * DMODEL + d] - mu3) * rs3 * lng[3 * DMODEL + d]
                             + lnb[3 * DMODEL + d]);
            float c = iv * zv;
            ctl[j] = c; ntl[j] = iv;
            s2[0] += c;  s2[1] += c * c;
            s2[2] += iv; s2[3] += iv * iv;
        }
        block_reduce<4>(s2, red);
        const float cmu = s2[0] * n1, crs = rsqrtf(s2[1] * n1 - cmu * cmu + LNEPS);
        const float nmu = s2[2] * n1, nrs = rsqrtf(s2[3] * n1 - nmu * nmu + LNEPS);

        for (int j = 0; j < 16; ++j) {
            const int d = t + 256 * j;
            ct_acc[j] += (ctl[j] - cmu) * crs * lng[4 * DMODEL + d] + lnb[4 * DMODEL + d];
            nt_acc[j] += (ntl[j] - nmu) * nrs * lng[5 * DMODEL + d] + lnb[5 * DMODEL + d];
            float ov = (p2[d] + bg[2 * DMODEL + d] - mu2) * rs2 * lng[2 * DMODEL + d]
                       + lnb[2 * DMODEL + d];
            ov = 1.f / (1.f + expf(-ov));
            obuf[(size_t)(row0 + rl) * DMODEL + d] = f2bf(ov);
        }
    }
    for (int j = 0; j < 16; ++j) {
        const int d = t + 256 * j;
        atomicAdd(&ctv[d], ct_acc[j]);
        atomicAdd(&ntv[d], nt_acc[j]);
    }
}

// ---------------- ht = o * (ctv/ntv), LN6 per row, accumulate row-mean ----------------
#define HROWS 16
__global__ __launch_bounds__(256) void htpass_k(
    const unsigned short* __restrict__ obuf,
    const float* __restrict__ ctv, const float* __restrict__ ntv,
    const float* __restrict__ lng, const float* __restrict__ lnb,
    float* __restrict__ htv)
{
    __shared__ float red[8];
    const int t = threadIdx.x;
    const float n1 = 1.f / DMODEL;
    float r[16], hacc[16] = {};
    for (int j = 0; j < 16; ++j) {
        const int d = t + 256 * j;
        r[j] = ctv[d] / ntv[d];      // ratio of sums == ratio of means
    }
    for (int rr = 0; rr < HROWS; ++rr) {
        const int row = blockIdx.x * HROWS + rr;
        float h[16]; float s[2] = {};
        for (int j = 0; j < 16; ++j) {
            const int d = t + 256 * j;
            h[j] = bf2f(obuf[(size_t)row * DMODEL + d]) * r[j];
            s[0] += h[j]; s[1] += h[j] * h[j];
        }
        block_reduce<2>(s, red);
        const float mu = s[0] * n1, rsv = rsqrtf(s[1] * n1 - mu * mu + LNEPS);
        for (int j = 0; j < 16; ++j) {
            const int d = t + 256 * j;
            hacc[j] += (h[j] - mu) * rsv * lng[6 * DMODEL + d] + lnb[6 * DMODEL + d];
        }
    }
    for (int j = 0; j < 16; ++j) {
        const int d = t + 256 * j;
        atomicAdd(&htv[d], hacc[j]);
    }
}

// ---------------- slstm_out = LN7(mean ht) ----------------
__global__ __launch_bounds__(256) void finalvec_k(
    const float* __restrict__ htv, const float* __restrict__ lng,
    const float* __restrict__ lnb, float* __restrict__ sout)
{
    __shared__ float red[8];
    const int t = threadIdx.x;
    const float n1 = 1.f / DMODEL;
    float v[16]; float s[2] = {};
    for (int j = 0; j < 16; ++j) {
        const int d = t + 256 * j;
        v[j] = htv[d] * (1.f / (float)NROWS);
        s[0] += v[j]; s[1] += v[j] * v[j];
    }
    block_reduce<2>(s, red);
    const float mu = s[0] * n1, rs = rsqrtf(s[1] * n1 - mu * mu + LNEPS);
    for (int j = 0; j < 16; ++j) {
        const int d = t + 256 * j;
        sout[d] = (v[j] - mu) * rs * lng[7 * DMODEL + d] + lnb[7 * DMODEL + d];
    }
}

// ---------------- left/right GEMV + exact gelu, one wave per output f ----------------
__global__ __launch_bounds__(256) void ffn1_k(
    const float* __restrict__ sout,
    const float* __restrict__ Wl, const float* __restrict__ bl,
    const float* __restrict__ Wr, const float* __restrict__ br,
    float* __restrict__ u)
{
    const int t = threadIdx.x, w = t >> 6, l = t & 63;
    const int f = blockIdx.x * 4 + w;
    if (f >= DFF) return;
    const float4* wl4 = (const float4*)(Wl + (size_t)f * DMODEL);
    const float4* wr4 = (const float4*)(Wr + (size_t)f * DMODEL);
    const float4* s4 = (const float4*)sout;
    float a = 0.f, b = 0.f;
#pragma unroll
    for (int jj = 0; jj < 16; ++jj) {
        const int i4 = l + 64 * jj;
        float4 sv = s4[i4], av = wl4[i4], bv = wr4[i4];
        a += sv.x * av.x + sv.y * av.y + sv.z * av.z + sv.w * av.w;
        b += sv.x * bv.x + sv.y * bv.y + sv.z * bv.z + sv.w * bv.w;
    }
#pragma unroll
    for (int off = 32; off > 0; off >>= 1) {
        a += __shfl_xor(a, off, 64);
        b += __shfl_xor(b, off, 64);
    }
    if (l == 0) {
        float lv = a + bl[f];
        float rv = b + br[f];
        float g = 0.5f * rv * (1.f + erff(rv * 0.70710678118654752f));  // exact gelu
        u[f] = lv * g;
    }
}

// ---------------- LN over DFF ----------------
__global__ __launch_bounds__(256) void lnout_k(
    const float* __restrict__ u, const float* __restrict__ g,
    const float* __restrict__ b, float* __restrict__ y)
{
    __shared__ float red[8];
    const int t = threadIdx.x;
    float s[2] = {};
    for (int d = t; d < DFF; d += 256) { float v = u[d]; s[0] += v; s[1] += v * v; }
    block_reduce<2>(s, red);
    const float n1 = 1.f / (float)DFF;
    const float mu = s[0] * n1, rs = rsqrtf(s[1] * n1 - mu * mu + LNEPS);
    for (int d = t; d < DFF; d += 256) y[d] = (u[d] - mu) * rs * g[d] + b[d];
}

// ---------------- proj GEMV, one wave per output d ----------------
__global__ __launch_bounds__(256) void ffn2_k(
    const float* __restrict__ y, const float* __restrict__ Wp,
    const float* __restrict__ bp, float* __restrict__ out)
{
    const int t = threadIdx.x, w = t >> 6, l = t & 63;
    const int d = blockIdx.x * 4 + w;
    const float* row = Wp + (size_t)d * DFF;
    float s = 0.f;
    for (int j = l; j < DFF; j += 64) s += row[j] * y[j];
#pragma unroll
    for (int off = 32; off > 0; off >>= 1) s += __shfl_xor(s, off, 64);
    if (l == 0) out[d] = s + bp[d];
}

extern "C" void kernel_launch(void* const* d_in, const int* in_sizes, int n_in,
                              void* d_out, int out_size, void* d_ws, size_t ws_size,
                              hipStream_t stream)
{
    const float* x   = (const float*)d_in[0];
    const float* Wg  = (const float*)d_in[1];
    const float* bg  = (const float*)d_in[2];
    // d_in[3] = Wr_gates: provably unused (ht_1 == 0)
    const float* lng = (const float*)d_in[4];
    const float* lnb = (const float*)d_in[5];
    const float* log_ = (const float*)d_in[6];
    const float* lob  = (const float*)d_in[7];
    const float* Wl  = (const float*)d_in[8];
    const float* bl  = (const float*)d_in[9];
    const float* Wr  = (const float*)d_in[10];
    const float* br  = (const float*)d_in[11];
    const float* Wp  = (const float*)d_in[12];
    const float* bp  = (const float*)d_in[13];
    float* out = (float*)d_out;

    char* ws = (char*)d_ws;
    size_t off = 0;
    _Float16* xh = (_Float16*)(ws + off); off += (size_t)NROWS * DMODEL * 2;        // 64 MB
    _Float16* xl = (_Float16*)(ws + off); off += (size_t)NROWS * DMODEL * 2;        // 64 MB
    _Float16* whp = (_Float16*)(ws + off); off += (size_t)16 * 1024 * 1024 * 2;     // 32 MB
    _Float16* wlp = (_Float16*)(ws + off); off += (size_t)16 * 1024 * 1024 * 2;     // 32 MB
    float* pre  = (float*)(ws + off); off += (size_t)4 * CHUNK * DMODEL * 4;        // 32 MB
    float* ctv  = (float*)(ws + off); off += DMODEL * 4;
    float* ntv  = (float*)(ws + off); off += DMODEL * 4;
    float* htv  = (float*)(ws + off); off += DMODEL * 4;
    float* sout = (float*)(ws + off); off += DMODEL * 4;
    float* u    = (float*)(ws + off); off += DFF * 4;
    float* y    = (float*)(ws + off); off += DFF * 4;

    // obuf aliases xl: chunk c's xl rows are last read by gemm(c), and obuf rows
    // [c*CHUNK, (c+1)*CHUNK) are written only by lnpass(c), which is stream-ordered
    // after gemm(c). htpass reads obuf after all chunks. Total ws stays at 224 MB.
    unsigned short* obuf = (unsigned short*)xl;

    // zero the global accumulators (ctv, ntv, htv are contiguous)
    hipMemsetAsync(ctv, 0, 3 * DMODEL * 4, stream);

    silu_split_k<<<(NROWS * DMODEL) / 1024, 256, 0, stream>>>(x, xh, xl);
    wsplit_k<<<(16 * 1024 * 1024) / 1024, 256, 0, stream>>>(Wg, whp, wlp);

    for (int c = 0; c < NCHUNK; ++c) {
        const int row0 = c * CHUNK;
        dim3 grid(1024 / GBN, CHUNK / GBM, 16);
        gemm_split_k<<<grid, 256, 0, stream>>>(xh, xl, whp, wlp, pre, row0);
        lnpass_k<<<CHUNK / EROWS, 256, 0, stream>>>(pre, bg, lng, lnb, obuf, ctv, ntv, row0);
    }

    htpass_k<<<NROWS / HROWS, 256, 0, stream>>>(obuf, ctv, ntv, lng, lnb, htv);
    finalvec_k<<<1, 256, 0, stream>>>(htv, lng, lnb, sout);
    ffn1_k<<<(DFF + 3) / 4, 256, 0, stream>>>(sout, Wl, bl, Wr, br, u);
    lnout_k<<<1, 256, 0, stream>>>(u, log_, lob, y);
    ffn2_k<<<DMODEL / 4, 256, 0, stream>>>(y, Wp, bp, out);

    (void)in_sizes; (void)n_in; (void)out_size; (void)ws_size;
}